// Round 6
// baseline (348.443 us; speedup 1.0000x reference)
//
#include <hip/hip_runtime.h>
#include <hip/hip_fp16.h>

#define N_NODES 100000
#define N_EDGES 1600000
#define E_TOT   (N_EDGES + N_NODES)
#define NEG_SLOPE 0.2f

#define BSH   9
#define BSZ   512                         // nodes per bucket
#define NBKT  ((N_NODES + BSZ - 1) / BSZ) // 196
#define CAP   10240                       // padded bucket capacity (mean 8673)
#define EPB   4096                        // edges per partition block
#define PART_B ((E_TOT + EPB - 1) / EPB)  // 416
#define GEMM1_B ((N_NODES + 63) / 64)     // 1563

__device__ __forceinline__ float lrelu(float v) { return v > 0.f ? v : NEG_SLOPE * v; }

__device__ __forceinline__ float f16lo(unsigned u) {
    return __half2float(__ushort_as_half((unsigned short)(u & 0xFFFFu)));
}
__device__ __forceinline__ float f16hi(unsigned u) {
    return __half2float(__ushort_as_half((unsigned short)(u >> 16)));
}

// ---- Fused launch 1: edge partition (blocks [0,PART_B)) + layer-1 GEMM ----
__global__ __launch_bounds__(256) void k_part_gemm1(
        const int* __restrict__ ei, int* __restrict__ gcur, int* __restrict__ packed,
        const float* __restrict__ x, const float* __restrict__ W1,
        const float* __restrict__ a_src, const float* __restrict__ a_dst,
        unsigned short* __restrict__ h1h, float* __restrict__ als,
        float* __restrict__ ald) {
    __shared__ __align__(16) union {
        float xs[64 * 128];                       // 32 KB (gemm1 role)
        struct { int lcnt[NBKT]; int gpos[NBKT]; int lcur[NBKT]; } p;  // part role
    } sm;
    int t = threadIdx.x;
    if (blockIdx.x < PART_B) {
        // ---------------- partition role ----------------
        for (int i = t; i < NBKT; i += 256) sm.p.lcnt[i] = 0;
        __syncthreads();
        size_t base = (size_t)blockIdx.x * EPB;
        for (int i = t; i < EPB; i += 256) {
            size_t e = base + i;
            if (e < E_TOT) {
                int d = (e < N_EDGES) ? ei[N_EDGES + e] : (int)(e - N_EDGES);
                atomicAdd(&sm.p.lcnt[d >> BSH], 1);
            }
        }
        __syncthreads();
        for (int i = t; i < NBKT; i += 256) {
            int c = sm.p.lcnt[i];
            sm.p.gpos[i] = c ? (i * CAP + atomicAdd(&gcur[i], c)) : 0;
            sm.p.lcur[i] = 0;
        }
        __syncthreads();
        for (int i = t; i < EPB; i += 256) {
            size_t e = base + i;
            if (e < E_TOT) {
                int s, d;
                if (e < N_EDGES) { s = ei[e]; d = ei[N_EDGES + e]; }
                else             { s = (int)(e - N_EDGES); d = s; }
                int b = d >> BSH;
                int c = atomicAdd(&sm.p.lcur[b], 1);
                packed[sm.p.gpos[b] + c] = ((d & (BSZ - 1)) << 17) | s;
            }
        }
        return;
    }
    // ---------------- gemm1 role ----------------
    int c = t & 31, rg = t >> 5;
    int nb = (blockIdx.x - PART_B) * 64;
    const float4* xv4 = (const float4*)x;
    float4* xs4 = (float4*)sm.xs;
    size_t base4 = (size_t)nb * 32;
    const size_t lim4 = (size_t)N_NODES * 32;
#pragma unroll
    for (int i = 0; i < 8; ++i) {
        size_t g = base4 + t + i * 256;
        if (g < lim4) xs4[t + i * 256] = xv4[g];
    }
    __syncthreads();
    const float4* W1v = (const float4*)W1;
    float4 acc[8];
#pragma unroll
    for (int i = 0; i < 8; ++i) acc[i] = make_float4(0.f, 0.f, 0.f, 0.f);
#pragma unroll 4
    for (int k = 0; k < 128; ++k) {
        float4 w = W1v[k * 32 + c];
#pragma unroll
        for (int i = 0; i < 8; ++i) {
            float xv = sm.xs[(rg + 8 * i) * 128 + k];
            acc[i].x = fmaf(xv, w.x, acc[i].x);
            acc[i].y = fmaf(xv, w.y, acc[i].y);
            acc[i].z = fmaf(xv, w.z, acc[i].z);
            acc[i].w = fmaf(xv, w.w, acc[i].w);
        }
    }
    float4 as4 = ((const float4*)a_src)[c];
    float4 ad4 = ((const float4*)a_dst)[c];
#pragma unroll
    for (int i = 0; i < 8; ++i) {
        int n = nb + rg + 8 * i;
        if (n < N_NODES) {
            ushort4 hb;
            hb.x = __half_as_ushort(__float2half(acc[i].x));
            hb.y = __half_as_ushort(__float2half(acc[i].y));
            hb.z = __half_as_ushort(__float2half(acc[i].z));
            hb.w = __half_as_ushort(__float2half(acc[i].w));
            ((ushort4*)h1h)[(size_t)n * 32 + c] = hb;
        }
        float vs = acc[i].x * as4.x + acc[i].y * as4.y + acc[i].z * as4.z + acc[i].w * as4.w;
        float vd = acc[i].x * ad4.x + acc[i].y * ad4.y + acc[i].z * ad4.z + acc[i].w * ad4.w;
        vs += __shfl_down(vs, 4, 8); vs += __shfl_down(vs, 2, 8); vs += __shfl_down(vs, 1, 8);
        vd += __shfl_down(vd, 4, 8); vd += __shfl_down(vd, 2, 8); vd += __shfl_down(vd, 1, 8);
        if ((c & 7) == 0 && n < N_NODES) {
            int h = c >> 3;
            als[n * 4 + h] = vs;
            ald[n * 4 + h] = vd;
        }
    }
}

// ---- per-bucket: count from cursor, local scan -> rowptr+deg, col scatter ----
__global__ __launch_bounds__(512) void k_build(const int* __restrict__ packed,
                                               const int* __restrict__ gcur,
                                               int* __restrict__ rowptr,
                                               int* __restrict__ deg,
                                               int* __restrict__ col) {
    int t = threadIdx.x;
    int b = blockIdx.x;
    int nb = b << BSH;
    int ebeg = b * CAP;
    int eend = ebeg + gcur[b];     // relative cursor
    __shared__ int cnt[BSZ];
    __shared__ int ps[BSZ];
    cnt[t] = 0;
    __syncthreads();
    for (int i = ebeg + t; i < eend; i += 512)
        atomicAdd(&cnt[packed[i] >> 17], 1);
    __syncthreads();
    int v = cnt[t];
    ps[t] = v;
    __syncthreads();
    for (int off = 1; off < 512; off <<= 1) {
        int u = (t >= off) ? ps[t - off] : 0;
        __syncthreads();
        ps[t] += u;
        __syncthreads();
    }
    int myofs = ebeg + ps[t] - v;   // padded-global col offset of node nb+t
    int n = nb + t;
    if (n < N_NODES) { rowptr[n] = myofs; deg[n] = v; }
    __syncthreads();
    cnt[t] = myofs;                  // reuse as global-position cursor
    __syncthreads();
    for (int i = ebeg + t; i < eend; i += 512) {
        int p = packed[i];
        int pos = atomicAdd(&cnt[p >> 17], 1);
        col[pos] = p & 0x1FFFF;
    }
}

// ---- Layer 1 aggregation + fused layer-2 GEMM/logits ----
// 4 nodes per wave: 16-lane group g owns node n end-to-end.
// cg = lane&15 handles channels 8cg..8cg+7 (16 B of the 256 B h1 row).
// W2 epilogue: each lane accumulates ALL 4 output quads over its 8 rows
// (work-efficient: 16 lanes x 8 rows x 16 cols = the full 128x16 GEMM),
// then a 4-level reduce-scatter butterfly (xor 8,4,2,1) leaves lane cg
// holding quad Q = cg>>2 summed over all 128 rows.
__global__ __launch_bounds__(256) void k_agg1g2(const unsigned short* __restrict__ h1h,
                                                const float* __restrict__ als,
                                                const float* __restrict__ ald,
                                                const int* __restrict__ rowptr,
                                                const int* __restrict__ deg,
                                                const int* __restrict__ col,
                                                const float* __restrict__ b1,
                                                const float* __restrict__ W2,
                                                const float* __restrict__ as2,
                                                const float* __restrict__ ad2,
                                                unsigned short* __restrict__ h2h,
                                                float* __restrict__ als2,
                                                float* __restrict__ ald2) {
    int w = threadIdx.x >> 6;
    int lane = threadIdx.x & 63;
    int g = lane >> 4, cg = lane & 15;
    int hd = cg >> 2;                         // head of channels 8cg..8cg+7
    int n = blockIdx.x * 16 + w * 4 + g;
    float adh = ald[n * 4 + hd];
    int beg = rowptr[n], dtot = deg[n];       // dtot >= 1 (self-loop)
    float a0 = 0.f, a1 = 0.f, a2 = 0.f, a3 = 0.f;
    float a4 = 0.f, a5 = 0.f, a6 = 0.f, a7 = 0.f, den = 0.f;
    int sv = col[beg];
    for (int e = 0; e < dtot; ++e) {
        int s = sv;
        sv = col[beg + min(e + 1, dtot - 1)];          // prefetch next col
        float al = als[s * 4 + hd];
        uint4 hv = *(const uint4*)((const char*)h1h + (((size_t)s << 8) + (cg << 4)));
        float ex = __expf(lrelu(al + adh));
        a0 = fmaf(ex, f16lo(hv.x), a0);
        a1 = fmaf(ex, f16hi(hv.x), a1);
        a2 = fmaf(ex, f16lo(hv.y), a2);
        a3 = fmaf(ex, f16hi(hv.y), a3);
        a4 = fmaf(ex, f16lo(hv.z), a4);
        a5 = fmaf(ex, f16hi(hv.z), a5);
        a6 = fmaf(ex, f16lo(hv.w), a6);
        a7 = fmaf(ex, f16hi(hv.w), a7);
        den += ex;
    }
    // ---- fused layer-2: o1 = relu(a/den + b1); h2 = o1 @ W2; logits ----
    float inv = 1.0f / den;                   // den is per-head (hd) — correct for these 8 ch
    float4 bA = ((const float4*)b1)[2 * cg];
    float4 bB = ((const float4*)b1)[2 * cg + 1];
    float o1v[8];
    o1v[0] = fmaxf(fmaf(a0, inv, bA.x), 0.f);
    o1v[1] = fmaxf(fmaf(a1, inv, bA.y), 0.f);
    o1v[2] = fmaxf(fmaf(a2, inv, bA.z), 0.f);
    o1v[3] = fmaxf(fmaf(a3, inv, bA.w), 0.f);
    o1v[4] = fmaxf(fmaf(a4, inv, bB.x), 0.f);
    o1v[5] = fmaxf(fmaf(a5, inv, bB.y), 0.f);
    o1v[6] = fmaxf(fmaf(a6, inv, bB.z), 0.f);
    o1v[7] = fmaxf(fmaf(a7, inv, bB.w), 0.f);
    // all 4 quads over rows 8cg..8cg+7
    const float4* W2v = (const float4*)W2;    // row-major [128][16] -> idx row*4 + quad
    float4 p0 = make_float4(0.f, 0.f, 0.f, 0.f);
    float4 p1 = make_float4(0.f, 0.f, 0.f, 0.f);
    float4 p2 = make_float4(0.f, 0.f, 0.f, 0.f);
    float4 p3 = make_float4(0.f, 0.f, 0.f, 0.f);
#pragma unroll
    for (int j = 0; j < 8; ++j) {
        float ov = o1v[j];
        int rb = (8 * cg + j) * 4;
        float4 w0 = W2v[rb + 0];
        float4 w1 = W2v[rb + 1];
        float4 w2 = W2v[rb + 2];
        float4 w3 = W2v[rb + 3];
        p0.x = fmaf(ov, w0.x, p0.x); p0.y = fmaf(ov, w0.y, p0.y);
        p0.z = fmaf(ov, w0.z, p0.z); p0.w = fmaf(ov, w0.w, p0.w);
        p1.x = fmaf(ov, w1.x, p1.x); p1.y = fmaf(ov, w1.y, p1.y);
        p1.z = fmaf(ov, w1.z, p1.z); p1.w = fmaf(ov, w1.w, p1.w);
        p2.x = fmaf(ov, w2.x, p2.x); p2.y = fmaf(ov, w2.y, p2.y);
        p2.z = fmaf(ov, w2.z, p2.z); p2.w = fmaf(ov, w2.w, p2.w);
        p3.x = fmaf(ov, w3.x, p3.x); p3.y = fmaf(ov, w3.y, p3.y);
        p3.z = fmaf(ov, w3.z, p3.z); p3.w = fmaf(ov, w3.w, p3.w);
    }
    // reduce-scatter butterfly over the 16-lane group
    // level 1 (xor 8): keep 2 quads
    bool b8 = (cg & 8) != 0;
    float4 s0, s1;
    {
        float4 q0 = b8 ? p2 : p0, q1 = b8 ? p3 : p1;   // values to keep
        float4 r0, r1, r2, r3;
        r0.x = __shfl_xor(p0.x, 8, 16); r0.y = __shfl_xor(p0.y, 8, 16);
        r0.z = __shfl_xor(p0.z, 8, 16); r0.w = __shfl_xor(p0.w, 8, 16);
        r1.x = __shfl_xor(p1.x, 8, 16); r1.y = __shfl_xor(p1.y, 8, 16);
        r1.z = __shfl_xor(p1.z, 8, 16); r1.w = __shfl_xor(p1.w, 8, 16);
        r2.x = __shfl_xor(p2.x, 8, 16); r2.y = __shfl_xor(p2.y, 8, 16);
        r2.z = __shfl_xor(p2.z, 8, 16); r2.w = __shfl_xor(p2.w, 8, 16);
        r3.x = __shfl_xor(p3.x, 8, 16); r3.y = __shfl_xor(p3.y, 8, 16);
        r3.z = __shfl_xor(p3.z, 8, 16); r3.w = __shfl_xor(p3.w, 8, 16);
        float4 u0 = b8 ? r2 : r0, u1 = b8 ? r3 : r1;
        s0.x = q0.x + u0.x; s0.y = q0.y + u0.y; s0.z = q0.z + u0.z; s0.w = q0.w + u0.w;
        s1.x = q1.x + u1.x; s1.y = q1.y + u1.y; s1.z = q1.z + u1.z; s1.w = q1.w + u1.w;
    }
    // level 2 (xor 4): keep 1 quad -> lane holds quad Q = cg>>2
    bool b4 = (cg & 4) != 0;
    float4 h2v;
    {
        float4 q = b4 ? s1 : s0;
        float4 r0, r1;
        r0.x = __shfl_xor(s0.x, 4, 16); r0.y = __shfl_xor(s0.y, 4, 16);
        r0.z = __shfl_xor(s0.z, 4, 16); r0.w = __shfl_xor(s0.w, 4, 16);
        r1.x = __shfl_xor(s1.x, 4, 16); r1.y = __shfl_xor(s1.y, 4, 16);
        r1.z = __shfl_xor(s1.z, 4, 16); r1.w = __shfl_xor(s1.w, 4, 16);
        float4 u = b4 ? r1 : r0;
        h2v.x = q.x + u.x; h2v.y = q.y + u.y; h2v.z = q.z + u.z; h2v.w = q.w + u.w;
    }
    // levels 3,4 (xor 2, xor 1): finish sum over all 16 lanes
    h2v.x += __shfl_xor(h2v.x, 2, 16); h2v.y += __shfl_xor(h2v.y, 2, 16);
    h2v.z += __shfl_xor(h2v.z, 2, 16); h2v.w += __shfl_xor(h2v.w, 2, 16);
    h2v.x += __shfl_xor(h2v.x, 1, 16); h2v.y += __shfl_xor(h2v.y, 1, 16);
    h2v.z += __shfl_xor(h2v.z, 1, 16); h2v.w += __shfl_xor(h2v.w, 1, 16);
    int Q = cg >> 2;
    if ((cg & 3) == 0) {
        ushort4 hb;
        hb.x = __half_as_ushort(__float2half(h2v.x));
        hb.y = __half_as_ushort(__float2half(h2v.y));
        hb.z = __half_as_ushort(__float2half(h2v.z));
        hb.w = __half_as_ushort(__float2half(h2v.w));
        ((ushort4*)h2h)[(size_t)n * 4 + Q] = hb;
    }
    float4 asv = ((const float4*)as2)[Q];
    float4 adv = ((const float4*)ad2)[Q];
    float vs = h2v.x * asv.x + h2v.y * asv.y + h2v.z * asv.z + h2v.w * asv.w;
    float vd = h2v.x * adv.x + h2v.y * adv.y + h2v.z * adv.z + h2v.w * adv.w;
    vs += __shfl_xor(vs, 4, 16); vs += __shfl_xor(vs, 8, 16);
    vd += __shfl_xor(vd, 4, 16); vd += __shfl_xor(vd, 8, 16);
    if (cg == 0) { als2[n] = vs; ald2[n] = vd; }
}

// ---- Layer 2 aggregation: 4 nodes/wave, 16-lane group per node ----
// Within group: es = edge slot (4 edges/iter), q = channel quad (uint2 = 8 B).
__global__ __launch_bounds__(256) void k_agg2(const unsigned short* __restrict__ h2h,
                                              const float* __restrict__ als,
                                              const float* __restrict__ ald,
                                              const int* __restrict__ rowptr,
                                              const int* __restrict__ deg,
                                              const int* __restrict__ col,
                                              const float* __restrict__ b2,
                                              float* __restrict__ out) {
    int w = threadIdx.x >> 6;
    int lane = threadIdx.x & 63;
    int g = lane >> 4, cg = lane & 15;
    int es = cg >> 2, q = cg & 3;
    int n = blockIdx.x * 16 + w * 4 + g;
    float adn = ald[n];
    int beg = rowptr[n], dtot = deg[n];
    float a0 = 0.f, a1 = 0.f, a2 = 0.f, a3 = 0.f, den = 0.f;
    for (int base = 0; base < dtot; base += 4) {
        int myq = base + es;
        int cq = min(myq, dtot - 1);
        int s = col[beg + cq];
        float ex = (myq < dtot) ? __expf(lrelu(als[s] + adn)) : 0.f;
        uint2 hv = *(const uint2*)((const char*)h2h + ((size_t)s * 32u + (q << 3)));
        a0 = fmaf(ex, f16lo(hv.x), a0);
        a1 = fmaf(ex, f16hi(hv.x), a1);
        a2 = fmaf(ex, f16lo(hv.y), a2);
        a3 = fmaf(ex, f16hi(hv.y), a3);
        den += ex;
    }
    // reduce over edge slots: lanes cg ^ 4, cg ^ 8 (width 16)
    a0 += __shfl_xor(a0, 4, 16); a1 += __shfl_xor(a1, 4, 16);
    a2 += __shfl_xor(a2, 4, 16); a3 += __shfl_xor(a3, 4, 16);
    den += __shfl_xor(den, 4, 16);
    a0 += __shfl_xor(a0, 8, 16); a1 += __shfl_xor(a1, 8, 16);
    a2 += __shfl_xor(a2, 8, 16); a3 += __shfl_xor(a3, 8, 16);
    den += __shfl_xor(den, 8, 16);
    if (es == 0) {
        float inv = 1.0f / den;
        float4 b4 = ((const float4*)b2)[q];
        float4 o;
        o.x = fmaf(a0, inv, b4.x);
        o.y = fmaf(a1, inv, b4.y);
        o.z = fmaf(a2, inv, b4.z);
        o.w = fmaf(a3, inv, b4.w);
        ((float4*)out)[(size_t)n * 4 + q] = o;
    }
}

extern "C" void kernel_launch(void* const* d_in, const int* in_sizes, int n_in,
                              void* d_out, int out_size, void* d_ws, size_t ws_size,
                              hipStream_t stream) {
    const float* x   = (const float*)d_in[0];
    const int*   ei  = (const int*)d_in[1];
    const float* W1  = (const float*)d_in[2];
    const float* as1 = (const float*)d_in[3];
    const float* ad1 = (const float*)d_in[4];
    const float* b1  = (const float*)d_in[5];
    const float* W2  = (const float*)d_in[6];
    const float* as2 = (const float*)d_in[7];
    const float* ad2 = (const float*)d_in[8];
    const float* b2  = (const float*)d_in[9];
    float* out = (float*)d_out;

    char* ws = (char*)d_ws;
    size_t off = 0;
    auto alloc = [&](size_t bytes) -> void* {
        void* p = ws + off;
        off += (bytes + 255) & ~(size_t)255;
        return p;
    };
    unsigned short* h1h = (unsigned short*)alloc((size_t)N_NODES * 128 * 2);
    float* als1v = (float*)alloc((size_t)N_NODES * 4 * 4);
    float* ald1v = (float*)alloc((size_t)N_NODES * 4 * 4);
    unsigned short* h2h = (unsigned short*)alloc((size_t)N_NODES * 16 * 2);
    float* als2v = (float*)alloc((size_t)N_NODES * 4);
    float* ald2v = (float*)alloc((size_t)N_NODES * 4);
    int* rowptr  = (int*)alloc((size_t)N_NODES * 4);
    int* degv    = (int*)alloc((size_t)N_NODES * 4);
    int* gcur    = (int*)alloc((size_t)NBKT * 4);
    int* packed  = (int*)alloc((size_t)NBKT * CAP * 4);
    int* colA    = (int*)alloc((size_t)NBKT * CAP * 4);

    hipMemsetAsync(gcur, 0, (size_t)NBKT * 4, stream);
    k_part_gemm1<<<PART_B + GEMM1_B, 256, 0, stream>>>(ei, gcur, packed,
                                                       x, W1, as1, ad1, h1h, als1v, ald1v);
    k_build<<<NBKT, 512, 0, stream>>>(packed, gcur, rowptr, degv, colA);
    k_agg1g2<<<N_NODES / 16, 256, 0, stream>>>(h1h, als1v, ald1v, rowptr, degv, colA,
                                               b1, W2, as2, ad2, h2h, als2v, ald2v);
    k_agg2<<<N_NODES / 16, 256, 0, stream>>>(h2h, als2v, ald2v, rowptr, degv, colA, b2, out);
}

// Round 13
// 306.464 us; speedup vs baseline: 1.1370x; 1.1370x over previous
//
#include <hip/hip_runtime.h>
#include <hip/hip_fp16.h>

#define N_NODES 100000
#define N_EDGES 1600000
#define E_TOT   (N_EDGES + N_NODES)
#define NEG_SLOPE 0.2f

#define BSH   9
#define BSZ   512                         // nodes per bucket
#define NBKT  ((N_NODES + BSZ - 1) / BSZ) // 196
#define CAP   10240                       // padded bucket capacity (mean 8673)
#define EPB   4096                        // edges per partition block
#define PART_B ((E_TOT + EPB - 1) / EPB)  // 416
#define GEMM1_B ((N_NODES + 63) / 64)     // 1563

__device__ __forceinline__ float lrelu(float v) { return v > 0.f ? v : NEG_SLOPE * v; }

__device__ __forceinline__ float f16lo(unsigned u) {
    return __half2float(__ushort_as_half((unsigned short)(u & 0xFFFFu)));
}
__device__ __forceinline__ float f16hi(unsigned u) {
    return __half2float(__ushort_as_half((unsigned short)(u >> 16)));
}
__device__ __forceinline__ unsigned packh2(float a, float b) {
    unsigned lo = __half_as_ushort(__float2half(a));
    unsigned hi = __half_as_ushort(__float2half(b));
    return (hi << 16) | lo;
}

// ---- Fused launch 1: edge partition (blocks [0,PART_B)) + layer-1 GEMM ----
__global__ __launch_bounds__(256) void k_part_gemm1(
        const int* __restrict__ ei, int* __restrict__ gcur, int* __restrict__ packed,
        const float* __restrict__ x, const float* __restrict__ W1,
        const float* __restrict__ a_src, const float* __restrict__ a_dst,
        unsigned short* __restrict__ h1h, float* __restrict__ als,
        float* __restrict__ ald) {
    __shared__ __align__(16) union {
        float xs[64 * 128];                       // 32 KB (gemm1 role)
        struct { int lcnt[NBKT]; int gpos[NBKT]; int lcur[NBKT]; } p;  // part role
    } sm;
    int t = threadIdx.x;
    if (blockIdx.x < PART_B) {
        // ---------------- partition role ----------------
        for (int i = t; i < NBKT; i += 256) sm.p.lcnt[i] = 0;
        __syncthreads();
        size_t base = (size_t)blockIdx.x * EPB;
        for (int i = t; i < EPB; i += 256) {
            size_t e = base + i;
            if (e < E_TOT) {
                int d = (e < N_EDGES) ? ei[N_EDGES + e] : (int)(e - N_EDGES);
                atomicAdd(&sm.p.lcnt[d >> BSH], 1);
            }
        }
        __syncthreads();
        for (int i = t; i < NBKT; i += 256) {
            int c = sm.p.lcnt[i];
            sm.p.gpos[i] = c ? (i * CAP + atomicAdd(&gcur[i], c)) : 0;
            sm.p.lcur[i] = 0;
        }
        __syncthreads();
        for (int i = t; i < EPB; i += 256) {
            size_t e = base + i;
            if (e < E_TOT) {
                int s, d;
                if (e < N_EDGES) { s = ei[e]; d = ei[N_EDGES + e]; }
                else             { s = (int)(e - N_EDGES); d = s; }
                int b = d >> BSH;
                int c = atomicAdd(&sm.p.lcur[b], 1);
                packed[sm.p.gpos[b] + c] = ((d & (BSZ - 1)) << 17) | s;
            }
        }
        return;
    }
    // ---------------- gemm1 role ----------------
    int c = t & 31, rg = t >> 5;
    int nb = (blockIdx.x - PART_B) * 64;
    const float4* xv4 = (const float4*)x;
    float4* xs4 = (float4*)sm.xs;
    size_t base4 = (size_t)nb * 32;
    const size_t lim4 = (size_t)N_NODES * 32;
#pragma unroll
    for (int i = 0; i < 8; ++i) {
        size_t g = base4 + t + i * 256;
        if (g < lim4) xs4[t + i * 256] = xv4[g];
    }
    __syncthreads();
    const float4* W1v = (const float4*)W1;
    float4 acc[8];
#pragma unroll
    for (int i = 0; i < 8; ++i) acc[i] = make_float4(0.f, 0.f, 0.f, 0.f);
#pragma unroll 4
    for (int k = 0; k < 128; ++k) {
        float4 w = W1v[k * 32 + c];
#pragma unroll
        for (int i = 0; i < 8; ++i) {
            float xv = sm.xs[(rg + 8 * i) * 128 + k];
            acc[i].x = fmaf(xv, w.x, acc[i].x);
            acc[i].y = fmaf(xv, w.y, acc[i].y);
            acc[i].z = fmaf(xv, w.z, acc[i].z);
            acc[i].w = fmaf(xv, w.w, acc[i].w);
        }
    }
    float4 as4 = ((const float4*)a_src)[c];
    float4 ad4 = ((const float4*)a_dst)[c];
#pragma unroll
    for (int i = 0; i < 8; ++i) {
        int n = nb + rg + 8 * i;
        if (n < N_NODES) {
            ushort4 hb;
            hb.x = __half_as_ushort(__float2half(acc[i].x));
            hb.y = __half_as_ushort(__float2half(acc[i].y));
            hb.z = __half_as_ushort(__float2half(acc[i].z));
            hb.w = __half_as_ushort(__float2half(acc[i].w));
            ((ushort4*)h1h)[(size_t)n * 32 + c] = hb;
        }
        float vs = acc[i].x * as4.x + acc[i].y * as4.y + acc[i].z * as4.z + acc[i].w * as4.w;
        float vd = acc[i].x * ad4.x + acc[i].y * ad4.y + acc[i].z * ad4.z + acc[i].w * ad4.w;
        vs += __shfl_down(vs, 4, 8); vs += __shfl_down(vs, 2, 8); vs += __shfl_down(vs, 1, 8);
        vd += __shfl_down(vd, 4, 8); vd += __shfl_down(vd, 2, 8); vd += __shfl_down(vd, 1, 8);
        if ((c & 7) == 0 && n < N_NODES) {
            int h = c >> 3;
            als[n * 4 + h] = vs;
            ald[n * 4 + h] = vd;
        }
    }
}

// ---- per-bucket: count from cursor, local scan -> rowptr+deg, col scatter ----
__global__ __launch_bounds__(512) void k_build(const int* __restrict__ packed,
                                               const int* __restrict__ gcur,
                                               int* __restrict__ rowptr,
                                               int* __restrict__ deg,
                                               int* __restrict__ col) {
    int t = threadIdx.x;
    int b = blockIdx.x;
    int nb = b << BSH;
    int ebeg = b * CAP;
    int eend = ebeg + gcur[b];     // relative cursor
    __shared__ int cnt[BSZ];
    __shared__ int ps[BSZ];
    cnt[t] = 0;
    __syncthreads();
    for (int i = ebeg + t; i < eend; i += 512)
        atomicAdd(&cnt[packed[i] >> 17], 1);
    __syncthreads();
    int v = cnt[t];
    ps[t] = v;
    __syncthreads();
    for (int off = 1; off < 512; off <<= 1) {
        int u = (t >= off) ? ps[t - off] : 0;
        __syncthreads();
        ps[t] += u;
        __syncthreads();
    }
    int myofs = ebeg + ps[t] - v;   // padded-global col offset of node nb+t
    int n = nb + t;
    if (n < N_NODES) { rowptr[n] = myofs; deg[n] = v; }
    __syncthreads();
    cnt[t] = myofs;                  // reuse as global-position cursor
    __syncthreads();
    for (int i = ebeg + t; i < eend; i += 512) {
        int p = packed[i];
        int pos = atomicAdd(&cnt[p >> 17], 1);
        col[pos] = p & 0x1FFFF;
    }
}

// ---- Layer 1 aggregation (round-0 structure): wave/node, 4 edges/iter uint4,
//      epilogue writes out1 as fp16 (halves write+read traffic for gemm2) ----
__global__ __launch_bounds__(256) void k_agg1(const unsigned short* __restrict__ h1h,
                                              const float* __restrict__ als,
                                              const float* __restrict__ ald,
                                              const int* __restrict__ rowptr,
                                              const int* __restrict__ deg,
                                              const int* __restrict__ col,
                                              const float* __restrict__ b1,
                                              unsigned short* __restrict__ out1h) {
    __shared__ float sex_all[4][64 * 4];   // per-wave ex[q][head]
    __shared__ int   scol_all[4][64];      // per-wave col cache
    int w = threadIdx.x >> 6;
    int lane = threadIdx.x & 63;
    int n = blockIdx.x * 4 + w;
    int slot = lane >> 4, cg = lane & 15;
    int hd = cg >> 2;
    float* sex = sex_all[w];
    int* scol = scol_all[w];
    float4 ald4 = ((const float4*)ald)[n];
    int beg = rowptr[n], dtot = deg[n];
    float a0 = 0.f, a1 = 0.f, a2 = 0.f, a3 = 0.f;
    float a4 = 0.f, a5 = 0.f, a6 = 0.f, a7 = 0.f, den = 0.f;
    const float4* als4p = (const float4*)als;
    for (int base = 0; base < dtot; base += 64) {
        int cnt = min(64, dtot - base);
        int myc = 0;
        if (lane < cnt) myc = col[beg + base + lane];
        // WAR: previous chunk's ds_reads must drain before overwriting LDS
        __asm__ volatile("s_waitcnt lgkmcnt(0)" ::: "memory");
        if (lane < cnt) {
            scol[lane] = myc;
            float4 as4 = als4p[myc];
            float4 e4;
            e4.x = __expf(lrelu(as4.x + ald4.x));
            e4.y = __expf(lrelu(as4.y + ald4.y));
            e4.z = __expf(lrelu(as4.z + ald4.z));
            e4.w = __expf(lrelu(as4.w + ald4.w));
            ((float4*)sex)[lane] = e4;
        }
        __asm__ volatile("s_waitcnt lgkmcnt(0)" ::: "memory");
#pragma unroll 2
        for (int q4 = 0; q4 < cnt; q4 += 4) {
            int myq = q4 + slot;
            int cq = min(myq, cnt - 1);
            int s = scol[cq];
            float ex = (myq < cnt) ? sex[cq * 4 + hd] : 0.f;
            uint4 hv = *(const uint4*)((const char*)h1h + (((size_t)s << 8) + (cg << 4)));
            a0 = fmaf(ex, f16lo(hv.x), a0);
            a1 = fmaf(ex, f16hi(hv.x), a1);
            a2 = fmaf(ex, f16lo(hv.y), a2);
            a3 = fmaf(ex, f16hi(hv.y), a3);
            a4 = fmaf(ex, f16lo(hv.z), a4);
            a5 = fmaf(ex, f16hi(hv.z), a5);
            a6 = fmaf(ex, f16lo(hv.w), a6);
            a7 = fmaf(ex, f16hi(hv.w), a7);
            den += ex;
        }
    }
    a0 += __shfl_xor(a0, 16, 64); a1 += __shfl_xor(a1, 16, 64);
    a2 += __shfl_xor(a2, 16, 64); a3 += __shfl_xor(a3, 16, 64);
    a4 += __shfl_xor(a4, 16, 64); a5 += __shfl_xor(a5, 16, 64);
    a6 += __shfl_xor(a6, 16, 64); a7 += __shfl_xor(a7, 16, 64);
    den += __shfl_xor(den, 16, 64);
    a0 += __shfl_xor(a0, 32, 64); a1 += __shfl_xor(a1, 32, 64);
    a2 += __shfl_xor(a2, 32, 64); a3 += __shfl_xor(a3, 32, 64);
    a4 += __shfl_xor(a4, 32, 64); a5 += __shfl_xor(a5, 32, 64);
    a6 += __shfl_xor(a6, 32, 64); a7 += __shfl_xor(a7, 32, 64);
    den += __shfl_xor(den, 32, 64);
    if (lane < 16) {
        float inv = 1.0f / den;
        float4 bA = ((const float4*)b1)[2 * lane];
        float4 bB = ((const float4*)b1)[2 * lane + 1];
        float o0 = fmaxf(fmaf(a0, inv, bA.x), 0.f);
        float o1 = fmaxf(fmaf(a1, inv, bA.y), 0.f);
        float o2 = fmaxf(fmaf(a2, inv, bA.z), 0.f);
        float o3 = fmaxf(fmaf(a3, inv, bA.w), 0.f);
        float o4 = fmaxf(fmaf(a4, inv, bB.x), 0.f);
        float o5 = fmaxf(fmaf(a5, inv, bB.y), 0.f);
        float o6 = fmaxf(fmaf(a6, inv, bB.z), 0.f);
        float o7 = fmaxf(fmaf(a7, inv, bB.w), 0.f);
        uint4 pk;
        pk.x = packh2(o0, o1);
        pk.y = packh2(o2, o3);
        pk.z = packh2(o4, o5);
        pk.w = packh2(o6, o7);
        ((uint4*)out1h)[(size_t)n * 16 + lane] = pk;  // ch 8*lane..8*lane+7
    }
}

// ---- Layer 2 GEMM: h2(fp16) = out1h(fp16) @ W2, fused logits ----
// LDS: x tile as f32 [16][132] + W2 transposed f32 [16][132]; inner loop
// reads float4 from both (64 ds_read_b128/thread vs 256 scalar before).
__global__ __launch_bounds__(256) void k_gemm2(const unsigned short* __restrict__ out1h,
                                               const float* __restrict__ W2,
                                               const float* __restrict__ a_src,
                                               const float* __restrict__ a_dst,
                                               unsigned short* __restrict__ h2h,
                                               float* __restrict__ als,
                                               float* __restrict__ ald) {
    __shared__ __align__(16) float xs[16 * 132];    // 8448 B
    __shared__ __align__(16) float w2t[16 * 132];   // 8448 B, W2T[c][k]
    int t = threadIdx.x;
    // stage W2 transposed: W2 row-major [128][16]
#pragma unroll
    for (int i = 0; i < 8; ++i) {
        int idx = t + i * 256;            // 0..2047
        int k = idx >> 4, c = idx & 15;
        w2t[c * 132 + k] = W2[idx];
    }
    // stage x tile: 16 nodes x 128 ch fp16 = 4 KB = 256 uint4
    {
        uint4 v = ((const uint4*)out1h)[(size_t)blockIdx.x * 256 + t];
        int node = t >> 4, cb = (t & 15) * 8;
        float* dst = &xs[node * 132 + cb];
        dst[0] = f16lo(v.x); dst[1] = f16hi(v.x);
        dst[2] = f16lo(v.y); dst[3] = f16hi(v.y);
        dst[4] = f16lo(v.z); dst[5] = f16hi(v.z);
        dst[6] = f16lo(v.w); dst[7] = f16hi(v.w);
    }
    __syncthreads();
    int r = t >> 4, c = t & 15;
    const float4* xr4 = (const float4*)&xs[r * 132];
    const float4* wr4 = (const float4*)&w2t[c * 132];
    float acc = 0.f;
#pragma unroll 8
    for (int k4 = 0; k4 < 32; ++k4) {
        float4 xv = xr4[k4];
        float4 wv = wr4[k4];
        acc = fmaf(xv.x, wv.x, acc);
        acc = fmaf(xv.y, wv.y, acc);
        acc = fmaf(xv.z, wv.z, acc);
        acc = fmaf(xv.w, wv.w, acc);
    }
    int n = blockIdx.x * 16 + r;
    h2h[(size_t)n * 16 + c] = __half_as_ushort(__float2half(acc));
    float vs = acc * a_src[c];
    float vd = acc * a_dst[c];
#pragma unroll
    for (int off = 8; off >= 1; off >>= 1) {
        vs += __shfl_down(vs, off, 16);
        vd += __shfl_down(vd, off, 16);
    }
    if (c == 0) { als[n] = vs; ald[n] = vd; }
}

// ---- Layer 2 aggregation: wave/node, 16 edges/iter, batched exp in LDS ----
__global__ __launch_bounds__(256) void k_agg2(const unsigned short* __restrict__ h2h,
                                              const float* __restrict__ als,
                                              const float* __restrict__ ald,
                                              const int* __restrict__ rowptr,
                                              const int* __restrict__ deg,
                                              const int* __restrict__ col,
                                              const float* __restrict__ b2,
                                              float* __restrict__ out) {
    __shared__ float sex_all[4][64];
    __shared__ int   scol_all[4][64];
    int w = threadIdx.x >> 6;
    int lane = threadIdx.x & 63;
    int n = blockIdx.x * 4 + w;
    int slot = lane >> 2, q = lane & 3;
    float* sex = sex_all[w];
    int* scol = scol_all[w];
    float ad = ald[n];
    int beg = rowptr[n], dtot = deg[n];
    float a0 = 0.f, a1 = 0.f, a2 = 0.f, a3 = 0.f, den = 0.f;
    for (int base = 0; base < dtot; base += 64) {
        int cnt = min(64, dtot - base);
        int myc = 0;
        if (lane < cnt) myc = col[beg + base + lane];
        __asm__ volatile("s_waitcnt lgkmcnt(0)" ::: "memory");
        if (lane < cnt) {
            scol[lane] = myc;
            sex[lane] = __expf(lrelu(als[myc] + ad));
        }
        __asm__ volatile("s_waitcnt lgkmcnt(0)" ::: "memory");
#pragma unroll 2
        for (int q16 = 0; q16 < cnt; q16 += 16) {
            int myq = q16 + slot;
            int cq = min(myq, cnt - 1);
            int s = scol[cq];
            float ex = (myq < cnt) ? sex[cq] : 0.f;
            uint2 hv = *(const uint2*)((const char*)h2h + ((size_t)s * 32u + (q << 3)));
            a0 = fmaf(ex, f16lo(hv.x), a0);
            a1 = fmaf(ex, f16hi(hv.x), a1);
            a2 = fmaf(ex, f16lo(hv.y), a2);
            a3 = fmaf(ex, f16hi(hv.y), a3);
            den += ex;
        }
    }
#pragma unroll
    for (int off = 4; off <= 32; off <<= 1) {
        a0 += __shfl_xor(a0, off, 64);
        a1 += __shfl_xor(a1, off, 64);
        a2 += __shfl_xor(a2, off, 64);
        a3 += __shfl_xor(a3, off, 64);
        den += __shfl_xor(den, off, 64);
    }
    if (slot == 0) {
        float inv = 1.0f / den;
        float4 b4 = ((const float4*)b2)[q];
        float4 o;
        o.x = fmaf(a0, inv, b4.x);
        o.y = fmaf(a1, inv, b4.y);
        o.z = fmaf(a2, inv, b4.z);
        o.w = fmaf(a3, inv, b4.w);
        ((float4*)out)[(size_t)n * 4 + q] = o;
    }
}

extern "C" void kernel_launch(void* const* d_in, const int* in_sizes, int n_in,
                              void* d_out, int out_size, void* d_ws, size_t ws_size,
                              hipStream_t stream) {
    const float* x   = (const float*)d_in[0];
    const int*   ei  = (const int*)d_in[1];
    const float* W1  = (const float*)d_in[2];
    const float* as1 = (const float*)d_in[3];
    const float* ad1 = (const float*)d_in[4];
    const float* b1  = (const float*)d_in[5];
    const float* W2  = (const float*)d_in[6];
    const float* as2 = (const float*)d_in[7];
    const float* ad2 = (const float*)d_in[8];
    const float* b2  = (const float*)d_in[9];
    float* out = (float*)d_out;

    char* ws = (char*)d_ws;
    size_t off = 0;
    auto alloc = [&](size_t bytes) -> void* {
        void* p = ws + off;
        off += (bytes + 255) & ~(size_t)255;
        return p;
    };
    unsigned short* h1h  = (unsigned short*)alloc((size_t)N_NODES * 128 * 2);
    unsigned short* o1h  = (unsigned short*)alloc((size_t)N_NODES * 128 * 2);
    float* als1v = (float*)alloc((size_t)N_NODES * 4 * 4);
    float* ald1v = (float*)alloc((size_t)N_NODES * 4 * 4);
    unsigned short* h2h = (unsigned short*)alloc((size_t)N_NODES * 16 * 2);
    float* als2v = (float*)alloc((size_t)N_NODES * 4);
    float* ald2v = (float*)alloc((size_t)N_NODES * 4);
    int* rowptr  = (int*)alloc((size_t)N_NODES * 4);
    int* degv    = (int*)alloc((size_t)N_NODES * 4);
    int* gcur    = (int*)alloc((size_t)NBKT * 4);
    int* packed  = (int*)alloc((size_t)NBKT * CAP * 4);
    int* colA    = (int*)alloc((size_t)NBKT * CAP * 4);

    hipMemsetAsync(gcur, 0, (size_t)NBKT * 4, stream);
    k_part_gemm1<<<PART_B + GEMM1_B, 256, 0, stream>>>(ei, gcur, packed,
                                                       x, W1, as1, ad1, h1h, als1v, ald1v);
    k_build<<<NBKT, 512, 0, stream>>>(packed, gcur, rowptr, degv, colA);
    k_agg1<<<N_NODES / 4, 256, 0, stream>>>(h1h, als1v, ald1v, rowptr, degv, colA, b1, o1h);
    k_gemm2<<<N_NODES / 16, 256, 0, stream>>>(o1h, W2, as2, ad2, h2h, als2v, ald2v);
    k_agg2<<<N_NODES / 4, 256, 0, stream>>>(h2h, als2v, ald2v, rowptr, degv, colA, b2, out);
}